// Round 1
// 335.159 us; speedup vs baseline: 1.0688x; 1.0688x over previous
//
#include <hip/hip_runtime.h>

#define N_NODES  50000
#define N_EDGES  800000
#define N_GRAPHS 128
#define HD       128
#define K2       256
#define CLS      10
#define NB_SCAN  ((N_NODES + 255) / 256)    // 196
#define NPART    8
#define PSIZE    (N_NODES / NPART)          // 6250
#define NBIN     400
#define CHUNK    (N_EDGES / NBIN)           // 2000
#define PCAP     131072

typedef __attribute__((ext_vector_type(8))) _Float16 f16x8;
typedef __attribute__((ext_vector_type(4))) float f32x4;
typedef __attribute__((ext_vector_type(2))) float f32x2;

union U4H8 { uint4 u; _Float16 h[8]; };
union U2H4 { uint2 u; _Float16 h[4]; };

typedef const __attribute__((address_space(1))) void* gptr_t;
typedef __attribute__((address_space(3))) void* lptr_t;
#define GLOAD_LDS16(g, l) \
    __builtin_amdgcn_global_load_lds((gptr_t)(g), (lptr_t)(l), 16, 0, 0)

// ---------------- zero deg + gcount (must precede initbin's atomics) ----------------
__global__ __launch_bounds__(256) void k_zero(int* __restrict__ z) {
    int i = blockIdx.x * 256 + threadIdx.x;
    if (i < 50008) z[i] = 0;
}

// ---------------- merged: edge binning (+deg atomics) || feature/weight init ----------------
// bin blocks first (critical path for CSR chain); init blocks fill the machine behind them
__global__ __launch_bounds__(256) void k_initbin(
    const float* __restrict__ f, unsigned short* __restrict__ c0, unsigned char* __restrict__ f8,
    const float* __restrict__ Ws0, const float* __restrict__ Wn0,
    const float* __restrict__ Ws1, const float* __restrict__ Wn1,
    const float* __restrict__ Ws2, const float* __restrict__ Wn2,
    unsigned short* __restrict__ wt, float* __restrict__ pooled,
    const int* __restrict__ gid, float* __restrict__ counts, int* __restrict__ bflag,
    const int* __restrict__ src, const int* __restrict__ dst,
    int2* __restrict__ stag, int* __restrict__ gcount, int* __restrict__ deg) {
    if (blockIdx.x < NBIN) {   // ======== bin part ========
        __shared__ int lcount[NPART];
        __shared__ int lbase[NPART];
        const int tid = threadIdx.x;
        const int lane = tid & 63;
        const int lo = blockIdx.x * CHUNK;
        if (tid < NPART) lcount[tid] = 0;
        __syncthreads();
        for (int i = lo + tid; i < lo + CHUNK; i += 256) {
            int d = dst[i];
            atomicAdd(&deg[d], 1);            // folded degree count (deg pre-zeroed by k_zero)
            int p = d / PSIZE;
#pragma unroll
            for (int q = 0; q < NPART; ++q) {
                unsigned long long m = __ballot(p == q);
                if (p == q) {
                    int leader = __ffsll((long long)m) - 1;
                    if (lane == leader) atomicAdd(&lcount[q], (int)__popcll(m));
                }
            }
        }
        __syncthreads();
        if (tid < NPART) {
            lbase[tid] = atomicAdd(&gcount[tid], lcount[tid]);
            lcount[tid] = 0;   // reuse as cursor
        }
        __syncthreads();
        for (int i = lo + tid; i < lo + CHUNK; i += 256) {
            int d = dst[i];
            int p = d / PSIZE;
            int slot = 0;
#pragma unroll
            for (int q = 0; q < NPART; ++q) {
                unsigned long long m = __ballot(p == q);
                if (p == q) {
                    int leader = __ffsll((long long)m) - 1;
                    int rank = (int)__popcll(m & ((1ull << lane) - 1ull));
                    int base;
                    if (lane == leader) base = atomicAdd(&lcount[q], (int)__popcll(m));
                    base = __shfl(base, leader);
                    slot = base + rank;
                }
            }
            stag[(size_t)p * PCAP + lbase[p] + slot] = make_int2(src[i], d);
        }
        return;
    }
    // ======== init part ========
    long long gi = (long long)(blockIdx.x - NBIN) * 256 + threadIdx.x;
    if (gi < 800000) {   // features: 8 elems/thread -> fp16 (K2-strided h-part) + fp8 row
        int t = (int)gi;
        int row = t >> 4, c8 = (t & 15) * 8;
        const float* p = f + (size_t)row * HD + c8;
        float4 a = *(const float4*)p;
        float4 b = *(const float4*)(p + 4);
        U4H8 v;
        v.h[0] = (_Float16)a.x; v.h[1] = (_Float16)a.y;
        v.h[2] = (_Float16)a.z; v.h[3] = (_Float16)a.w;
        v.h[4] = (_Float16)b.x; v.h[5] = (_Float16)b.y;
        v.h[6] = (_Float16)b.z; v.h[7] = (_Float16)b.w;
        *(uint4*)(c0 + (size_t)row * K2 + c8) = v.u;
        int p0 = __builtin_amdgcn_cvt_pk_fp8_f32(a.x, a.y, 0, false);
        p0 = __builtin_amdgcn_cvt_pk_fp8_f32(a.z, a.w, p0, true);
        int p1 = __builtin_amdgcn_cvt_pk_fp8_f32(b.x, b.y, 0, false);
        p1 = __builtin_amdgcn_cvt_pk_fp8_f32(b.z, b.w, p1, true);
        *(uint2*)(f8 + (size_t)row * HD + c8) = make_uint2((unsigned)p0, (unsigned)p1);
        return;
    }
    gi -= 800000;
    if (gi < 3 * HD * K2) {   // weights: transpose+concat -> fp16 [l][n][k]
        int t = (int)gi;
        int l = t / (HD * K2), r = t % (HD * K2);
        int n = r / K2, k = r % K2;
        const float* Ws = (l == 0) ? Ws0 : (l == 1) ? Ws1 : Ws2;
        const float* Wn = (l == 0) ? Wn0 : (l == 1) ? Wn1 : Wn2;
        float w = (k < HD) ? Ws[k * HD + n] : Wn[(k - HD) * HD + n];
        union { unsigned short u; _Float16 h; } c;
        c.h = (_Float16)w;
        wt[t] = c.u;
        return;
    }
    gi -= 3 * HD * K2;
    if (gi < N_GRAPHS * HD) { pooled[gi] = 0.f; return; }
    gi -= (long long)N_GRAPHS * HD;
    if (gi < N_GRAPHS) {   // graph counts via binary search (gid sorted)
        int g = (int)gi;
        int lo = 0, hi = N_NODES;
        while (lo < hi) { int mid = (lo + hi) >> 1; if (gid[mid] < g) lo = mid + 1; else hi = mid; }
        int start = lo;
        lo = 0; hi = N_NODES;
        while (lo < hi) { int mid = (lo + hi) >> 1; if (gid[mid] <= g) lo = mid + 1; else hi = mid; }
        counts[g] = (float)(lo - start);
        return;
    }
    gi -= N_GRAPHS;
    if (gi < 256) bflag[gi] = 0;   // lookback flags for k_scan
}
#define INIT_ITEMS (800000 + 3 * HD * K2 + N_GRAPHS * HD + N_GRAPHS + 256)
#define INIT_BLOCKS ((INIT_ITEMS + 255) / 256)

// ---------------- single-pass exclusive scan: local scan + decoupled lookback (aggregates) ----------------
__global__ __launch_bounds__(256) void k_scan(const int* __restrict__ deg,
                                              int* __restrict__ rowptr, int* __restrict__ cursor,
                                              int* __restrict__ bsum, int* __restrict__ bflag) {
    __shared__ int s[256];
    __shared__ int r[256];
    const int tid = threadIdx.x;
    const int b = blockIdx.x;
    const int i = b * 256 + tid;
    int v = (i < N_NODES) ? deg[i] : 0;
    s[tid] = v;
    __syncthreads();
    for (int off = 1; off < 256; off <<= 1) {
        int add = (tid >= off) ? s[tid - off] : 0;
        __syncthreads();
        s[tid] += add;
        __syncthreads();
    }
    if (tid == 255) {   // publish block aggregate, then release flag
        __hip_atomic_store(&bsum[b], s[255], __ATOMIC_RELAXED, __HIP_MEMORY_SCOPE_AGENT);
        __hip_atomic_store(&bflag[b], 1, __ATOMIC_RELEASE, __HIP_MEMORY_SCOPE_AGENT);
    }
    int agg = 0;
    if (tid < b) {   // 196 blocks <= CU count: all co-resident, no deadlock
        while (__hip_atomic_load(&bflag[tid], __ATOMIC_ACQUIRE, __HIP_MEMORY_SCOPE_AGENT) == 0) {}
        agg = __hip_atomic_load(&bsum[tid], __ATOMIC_RELAXED, __HIP_MEMORY_SCOPE_AGENT);
    }
    r[tid] = agg;
    __syncthreads();
    for (int off = 128; off > 0; off >>= 1) {
        if (tid < off) r[tid] += r[tid + off];
        __syncthreads();
    }
    if (i < N_NODES) {
        int val = r[0] + s[tid] - v;
        rowptr[i] = val;
        cursor[i] = val;
    }
    if (b == NB_SCAN - 1 && tid == 0) rowptr[N_NODES] = N_EDGES;
}

// ---------------- CSR fill from staged pairs (XCD-local) ----------------
__global__ __launch_bounds__(256) void k_fill2(const int2* __restrict__ stag, const int* __restrict__ gcount,
                                               int* __restrict__ cursor, int* __restrict__ eidx) {
    const int part = blockIdx.x & (NPART - 1);
    const int blk = blockIdx.x >> 3;
    const int n = gcount[part];
    const int2* s = stag + (size_t)part * PCAP;
    for (int i = blk * 256 + threadIdx.x; i < n; i += 64 * 256) {
        int2 e = s[i];
        int pos = atomicAdd(&cursor[e.y], 1);
        eidx[pos] = e.x;
    }
}

// ---------------- gather: one wave per node, fp8 rows, fp32 accum, 16 edges in flight ----------------
__global__ __launch_bounds__(256) void k_gather(const unsigned char* __restrict__ h8,
                                                const int* __restrict__ rowptr,
                                                const int* __restrict__ eidx,
                                                unsigned short* __restrict__ msg) {
    const int node = (blockIdx.x * 256 + threadIdx.x) >> 6;
    const int lane = threadIdx.x & 63;
    if (node >= N_NODES) return;
    const int epar = lane >> 4;        // 4 edge slots
    const int d0 = (lane & 15) * 8;    // 8 fp8 per lane = 8 B
    const int beg = rowptr[node], end = rowptr[node + 1];
    float acc[8] = {0.f, 0.f, 0.f, 0.f, 0.f, 0.f, 0.f, 0.f};
    int j = beg + epar;
    for (; j + 12 < end; j += 16) {    // 16 edges in flight per wave
        int s0 = eidx[j], s1 = eidx[j + 4], s2 = eidx[j + 8], s3 = eidx[j + 12];
        uint2 v0 = *(const uint2*)(h8 + (size_t)s0 * HD + d0);
        uint2 v1 = *(const uint2*)(h8 + (size_t)s1 * HD + d0);
        uint2 v2 = *(const uint2*)(h8 + (size_t)s2 * HD + d0);
        uint2 v3 = *(const uint2*)(h8 + (size_t)s3 * HD + d0);
        f32x2 e;
        e = __builtin_amdgcn_cvt_pk_f32_fp8(v0.x, false); acc[0] += e[0]; acc[1] += e[1];
        e = __builtin_amdgcn_cvt_pk_f32_fp8(v0.x, true);  acc[2] += e[0]; acc[3] += e[1];
        e = __builtin_amdgcn_cvt_pk_f32_fp8(v0.y, false); acc[4] += e[0]; acc[5] += e[1];
        e = __builtin_amdgcn_cvt_pk_f32_fp8(v0.y, true);  acc[6] += e[0]; acc[7] += e[1];
        e = __builtin_amdgcn_cvt_pk_f32_fp8(v1.x, false); acc[0] += e[0]; acc[1] += e[1];
        e = __builtin_amdgcn_cvt_pk_f32_fp8(v1.x, true);  acc[2] += e[0]; acc[3] += e[1];
        e = __builtin_amdgcn_cvt_pk_f32_fp8(v1.y, false); acc[4] += e[0]; acc[5] += e[1];
        e = __builtin_amdgcn_cvt_pk_f32_fp8(v1.y, true);  acc[6] += e[0]; acc[7] += e[1];
        e = __builtin_amdgcn_cvt_pk_f32_fp8(v2.x, false); acc[0] += e[0]; acc[1] += e[1];
        e = __builtin_amdgcn_cvt_pk_f32_fp8(v2.x, true);  acc[2] += e[0]; acc[3] += e[1];
        e = __builtin_amdgcn_cvt_pk_f32_fp8(v2.y, false); acc[4] += e[0]; acc[5] += e[1];
        e = __builtin_amdgcn_cvt_pk_f32_fp8(v2.y, true);  acc[6] += e[0]; acc[7] += e[1];
        e = __builtin_amdgcn_cvt_pk_f32_fp8(v3.x, false); acc[0] += e[0]; acc[1] += e[1];
        e = __builtin_amdgcn_cvt_pk_f32_fp8(v3.x, true);  acc[2] += e[0]; acc[3] += e[1];
        e = __builtin_amdgcn_cvt_pk_f32_fp8(v3.y, false); acc[4] += e[0]; acc[5] += e[1];
        e = __builtin_amdgcn_cvt_pk_f32_fp8(v3.y, true);  acc[6] += e[0]; acc[7] += e[1];
    }
    for (; j < end; j += 4) {
        uint2 v0 = *(const uint2*)(h8 + (size_t)eidx[j] * HD + d0);
        f32x2 e;
        e = __builtin_amdgcn_cvt_pk_f32_fp8(v0.x, false); acc[0] += e[0]; acc[1] += e[1];
        e = __builtin_amdgcn_cvt_pk_f32_fp8(v0.x, true);  acc[2] += e[0]; acc[3] += e[1];
        e = __builtin_amdgcn_cvt_pk_f32_fp8(v0.y, false); acc[4] += e[0]; acc[5] += e[1];
        e = __builtin_amdgcn_cvt_pk_f32_fp8(v0.y, true);  acc[6] += e[0]; acc[7] += e[1];
    }
#pragma unroll
    for (int i = 0; i < 8; ++i) {
        acc[i] += __shfl_xor(acc[i], 16);
        acc[i] += __shfl_xor(acc[i], 32);
    }
    if (epar == 0) {
        float inv = (end > beg) ? 1.0f / (float)(end - beg) : 0.f;
        U4H8 o;
#pragma unroll
        for (int i = 0; i < 8; ++i) o.h[i] = (_Float16)(acc[i] * inv);
        *(uint4*)(msg + (size_t)node * K2 + HD + d0) = o.u;
    }
}

// ---------------- SAGE layer v2: global_load_lds (w16), dbuf K-step 64, XOR chunk swizzle ----------------
// LDS linear [128][64] halfs per tile; logical 16B-chunk q of row r stored at phys chunk q^(r&7)
// -> staging pre-swizzles the GLOBAL source per lane (rule: both-sides-or-neither), ds_read applies
//    the same XOR; 16 lanes x stride-128B rows then alias banks only 2-way (free).
__global__ __launch_bounds__(256) void k_sage(const unsigned short* __restrict__ hin,  // [m][256] fp16
                                              const unsigned short* __restrict__ wt,   // [n][256] fp16
                                              const float* __restrict__ bias,
                                              unsigned short* __restrict__ hout,       // [m][256] h-part
                                              unsigned char* __restrict__ hout8,       // [m][128] fp8
                                              int write16) {
    __shared__ __align__(16) _Float16 Ah[2][128 * 64];
    __shared__ __align__(16) _Float16 Bw[2][128 * 64];
    const int tid = threadIdx.x;
    const int wv = tid >> 6, lane = tid & 63;
    const int m0 = blockIdx.x * 128;
    const int m_off = (wv >> 1) * 64, n_off = (wv & 1) * 64;
    const int l15 = lane & 15, q = lane >> 4;

    f32x4 acc[4][4];
#pragma unroll
    for (int a = 0; a < 4; ++a)
#pragma unroll
        for (int b = 0; b < 4; ++b) acc[a][b] = (f32x4){0.f, 0.f, 0.f, 0.f};

    auto stage = [&](int bsel, int kt) {
        const int k0 = kt * 64;
#pragma unroll
        for (int i = 0; i < 4; ++i) {
            int idx = tid + i * 256;             // 1024 16B-chunks per operand tile
            int row = idx >> 3, c = idx & 7;
            int qs = (c ^ (row & 7)) * 8;        // pre-swizzled source chunk (halfs)
            int gm = m0 + row;
            if (gm < N_NODES)
                GLOAD_LDS16(hin + (size_t)gm * K2 + k0 + qs, &Ah[bsel][idx * 8]);
            GLOAD_LDS16(wt + (size_t)row * K2 + k0 + qs, &Bw[bsel][idx * 8]);
        }
    };

    stage(0, 0);
    __syncthreads();   // drains vmcnt(0): buf0 ready
#pragma unroll
    for (int kt = 0; kt < 4; ++kt) {
        const int b = kt & 1;
        if (kt < 3) stage(b ^ 1, kt + 1);        // prefetch next tile into other buffer
        f16x8 hf[4][2], wf[4][2];
#pragma unroll
        for (int mt = 0; mt < 4; ++mt) {
            const int row = m_off + mt * 16 + l15;
            const int sw = row & 7;
#pragma unroll
            for (int ks = 0; ks < 2; ++ks)
                hf[mt][ks] = *(const f16x8*)&Ah[b][row * 64 + (((ks * 4 + q) ^ sw) * 8)];
        }
#pragma unroll
        for (int nt = 0; nt < 4; ++nt) {
            const int row = n_off + nt * 16 + l15;
            const int sw = row & 7;
#pragma unroll
            for (int ks = 0; ks < 2; ++ks)
                wf[nt][ks] = *(const f16x8*)&Bw[b][row * 64 + (((ks * 4 + q) ^ sw) * 8)];
        }
#pragma unroll
        for (int mt = 0; mt < 4; ++mt)
#pragma unroll
            for (int nt = 0; nt < 4; ++nt) {
                acc[mt][nt] = __builtin_amdgcn_mfma_f32_16x16x32_f16(wf[nt][0], hf[mt][0], acc[mt][nt], 0, 0, 0);
                acc[mt][nt] = __builtin_amdgcn_mfma_f32_16x16x32_f16(wf[nt][1], hf[mt][1], acc[mt][nt], 0, 0, 0);
            }
        __syncthreads();   // next buffer's loads landed; all waves done reading buf b
    }
#pragma unroll
    for (int nt = 0; nt < 4; ++nt) {
        int n = n_off + nt * 16 + q * 4;
        float4 bv = *(const float4*)(bias + n);
#pragma unroll
        for (int mt = 0; mt < 4; ++mt) {
            int m = m0 + m_off + mt * 16 + l15;
            if (m < N_NODES) {
                f32x4 a = acc[mt][nt];
                float r0 = fmaxf(a[0] + bv.x, 0.f);
                float r1 = fmaxf(a[1] + bv.y, 0.f);
                float r2 = fmaxf(a[2] + bv.z, 0.f);
                float r3 = fmaxf(a[3] + bv.w, 0.f);
                if (write16) {
                    U2H4 v;
                    v.h[0] = (_Float16)r0; v.h[1] = (_Float16)r1;
                    v.h[2] = (_Float16)r2; v.h[3] = (_Float16)r3;
                    *(uint2*)(hout + (size_t)m * K2 + n) = v.u;
                }
                int p = __builtin_amdgcn_cvt_pk_fp8_f32(r0, r1, 0, false);
                p = __builtin_amdgcn_cvt_pk_fp8_f32(r2, r3, p, true);
                *(unsigned int*)(hout8 + (size_t)m * HD + n) = (unsigned)p;
            }
        }
    }
}

// ---------------- graph mean-pool from fp8 shadow (sorted gids) ----------------
__global__ __launch_bounds__(256) void k_pool(const unsigned char* __restrict__ h8,
                                              const int* __restrict__ gid,
                                              float* __restrict__ pooled) {
    const int p2 = (threadIdx.x & 63) * 2;   // dim pair
    const int sl = threadIdx.x >> 6;         // node slice 0..3
    const int n0 = blockIdx.x * 128;
    float a0 = 0.f, a1 = 0.f;
    int cur = -1;
    for (int i = sl; i < 128; i += 4) {
        int n = n0 + i;
        if (n >= N_NODES) break;
        int g = gid[n];
        if (g != cur) {
            if (cur >= 0) {
                atomicAdd(&pooled[(size_t)cur * HD + p2], a0);
                atomicAdd(&pooled[(size_t)cur * HD + p2 + 1], a1);
            }
            a0 = 0.f; a1 = 0.f;
            cur = g;
        }
        unsigned short v = *(const unsigned short*)(h8 + (size_t)n * HD + p2);
        f32x2 e = __builtin_amdgcn_cvt_pk_f32_fp8((unsigned)v, false);
        a0 += e[0]; a1 += e[1];
    }
    if (cur >= 0) {
        atomicAdd(&pooled[(size_t)cur * HD + p2], a0);
        atomicAdd(&pooled[(size_t)cur * HD + p2 + 1], a1);
    }
}

// ---------------- classifier (fp32) ----------------
__global__ __launch_bounds__(256) void k_final(const float* __restrict__ pooled,
                                               const float* __restrict__ counts,
                                               const float* __restrict__ Wf,
                                               const float* __restrict__ bf,
                                               float* __restrict__ out) {
    int t = blockIdx.x * 256 + threadIdx.x;
    if (t >= N_GRAPHS * CLS) return;
    int g = t / CLS, c = t % CLS;
    float inv = 1.0f / fmaxf(counts[g], 1.0f);
    float s = 0.f;
    for (int k = 0; k < HD; ++k) s += pooled[(size_t)g * HD + k] * Wf[k * CLS + c];
    out[t] = s * inv + bf[c];
}

extern "C" void kernel_launch(void* const* d_in, const int* in_sizes, int n_in,
                              void* d_out, int out_size, void* d_ws, size_t ws_size,
                              hipStream_t stream) {
    const float* features = (const float*)d_in[0];
    const int*   esrc     = (const int*)d_in[1];
    const int*   edst     = (const int*)d_in[2];
    const int*   gids     = (const int*)d_in[3];
    const float* bs[3]  = {(const float*)d_in[6], (const float*)d_in[9], (const float*)d_in[12]};
    const float* Wf = (const float*)d_in[13];
    const float* bfv = (const float*)d_in[14];
    float* out = (float*)d_out;

    int* deg_i  = (int*)d_ws;            // 50000 + gcount(8): zeroed by k_zero
    int* gcount = deg_i + 50000;
    int* rowptr = deg_i + 50064;
    int* cursor = rowptr + 50064;
    int* bsum   = cursor + 50048;
    int* bflag  = bsum + 256;            // zeroed by initbin init-part
    int* eidx   = bflag + 256;
    int2* stag  = (int2*)(eidx + 800000);
    float* pooled = (float*)(stag + (size_t)NPART * PCAP);
    float* counts = pooled + N_GRAPHS * HD;
    unsigned short* C0 = (unsigned short*)(counts + 128);    // 50000*256 fp16 x3 (h|msg)
    unsigned short* C1 = C0 + (size_t)N_NODES * K2;
    unsigned short* C2 = C1 + (size_t)N_NODES * K2;
    unsigned short* Wt = C2 + (size_t)N_NODES * K2;
    unsigned char* F0 = (unsigned char*)(Wt + 3 * HD * K2);
    unsigned char* F1 = F0 + (size_t)N_NODES * HD;
    unsigned char* F2 = F1 + (size_t)N_NODES * HD;

    k_zero<<<196, 256, 0, stream>>>(deg_i);

    k_initbin<<<NBIN + INIT_BLOCKS, 256, 0, stream>>>(
        features, C0, F0,
        (const float*)d_in[4], (const float*)d_in[5],
        (const float*)d_in[7], (const float*)d_in[8],
        (const float*)d_in[10], (const float*)d_in[11],
        Wt, pooled, gids, counts, bflag,
        esrc, edst, stag, gcount, deg_i);

    k_scan<<<NB_SCAN, 256, 0, stream>>>(deg_i, rowptr, cursor, bsum, bflag);
    k_fill2<<<NPART * 64, 256, 0, stream>>>(stag, gcount, cursor, eidx);

    unsigned short* C[4] = {C0, C1, C2, C0};
    unsigned char* F[4] = {F0, F1, F2, F0};
    for (int l = 0; l < 3; ++l) {
        k_gather<<<(N_NODES * 64 + 255) / 256, 256, 0, stream>>>(F[l], rowptr, eidx, C[l]);
        k_sage<<<(N_NODES + 127) / 128, 256, 0, stream>>>(
            C[l], Wt + (size_t)l * HD * K2, bs[l], C[l + 1], F[l + 1], (l < 2) ? 1 : 0);
    }

    // pool reads the fp8 shadow of layer-3 output (F0)
    k_pool<<<(N_NODES + 127) / 128, 256, 0, stream>>>(F0, gids, pooled);
    k_final<<<(N_GRAPHS * CLS + 255) / 256, 256, 0, stream>>>(pooled, counts, Wf, bfv, out);
}